// Round 1
// baseline (56.345 us; speedup 1.0000x reference)
//
#include <hip/hip_runtime.h>

// Pattern 'D' temporal shifts per (row%4, col%4), mult = +1 (INV=False)
__device__ __constant__ int c_pat[16] = {
     0,  1,  2,  3,
    -1, -7,  4,  5,
     2, -4,  7,  6,
    -3, -5, -6,  8,
};

// Fixed problem geometry from setup_inputs():
//   batch_size=16, frame_len(T)=16, B=256, H=12, N=196 (14x14), c=64, fp32
constexpr int H   = 12;
constexpr int N   = 196;
constexpr int C   = 64;
constexpr int T   = 16;
constexpr int NS  = 14;
constexpr int ROW_F4   = C / 4;            // 16 float4 per (b,h,n) row
constexpr int PLANE_F4 = H * N * C / 4;    // float4 per b-slice = 37632

__global__ __launch_bounds__(256) void patch_shift_kernel(
    const float4* __restrict__ in, float4* __restrict__ out, int total_f4)
{
    int idx = blockIdx.x * blockDim.x + threadIdx.x;
    if (idx >= total_f4) return;

    int row = idx >> 4;            // (b*H + h)*N + n
    int n   = row % N;             // patch index within 14x14 grid
    int bh  = row / N;
    int b   = bh / H;              // bs*T + t
    int t   = b & (T - 1);

    int i = n / NS;                // patch row
    int j = n - i * NS;            // patch col
    int s = c_pat[((i & 3) << 2) | (j & 3)];

    int src_t = (t - s + 16) & 15; // (t - s) mod 16, s in [-7,8]
    int delta = src_t - t;         // shift in b-units

    out[idx] = in[idx + delta * PLANE_F4];
}

extern "C" void kernel_launch(void* const* d_in, const int* in_sizes, int n_in,
                              void* d_out, int out_size, void* d_ws, size_t ws_size,
                              hipStream_t stream) {
    const float4* in  = (const float4*)d_in[0];
    float4*       out = (float4*)d_out;

    int total_f4 = in_sizes[0] / 4;          // 9,633,792
    int block = 256;
    int grid  = (total_f4 + block - 1) / block;  // 37,632

    patch_shift_kernel<<<grid, block, 0, stream>>>(in, out, total_f4);
}

// Round 3
// 54.300 us; speedup vs baseline: 1.0377x; 1.0377x over previous
//
#include <hip/hip_runtime.h>

// Native 16B vector type accepted by __builtin_nontemporal_*.
typedef float f4 __attribute__((ext_vector_type(4)));

// Pattern 'D' temporal shifts per (row%4, col%4), mult = +1 (INV=False)
__device__ __constant__ int c_pat[16] = {
     0,  1,  2,  3,
    -1, -7,  4,  5,
     2, -4,  7,  6,
    -3, -5, -6,  8,
};

// Fixed problem geometry from setup_inputs():
//   batch_size=16, frame_len(T)=16, B=256, H=12, N=196 (14x14), c=64, fp32
constexpr int H   = 12;
constexpr int N   = 196;
constexpr int C   = 64;
constexpr int T   = 16;
constexpr int NS  = 14;
constexpr int PLANE_F4 = H * N * C / 4;    // float4 per b-slice = 37632
constexpr int F4_PER_THREAD = 4;
constexpr int BLOCK = 256;

__global__ __launch_bounds__(BLOCK) void patch_shift_kernel(
    const f4* __restrict__ in, f4* __restrict__ out, int total_f4)
{
    int base = blockIdx.x * (BLOCK * F4_PER_THREAD) + threadIdx.x;

    f4  v[F4_PER_THREAD];
    int dst[F4_PER_THREAD];

    // Issue all loads first (independent -> 4 outstanding per lane),
    // each sub-access wave-coalesced (stride BLOCK between sub-accesses).
#pragma unroll
    for (int u = 0; u < F4_PER_THREAD; ++u) {
        int idx = base + u * BLOCK;
        dst[u] = idx;

        int row = idx >> 4;            // (b*H + h)*N + n
        int n   = row % N;             // patch index within 14x14 grid
        int bh  = row / N;
        int b   = bh / H;              // bs*T + t
        int t   = b & (T - 1);

        int i = n / NS;                // patch row
        int j = n - i * NS;            // patch col
        int s = c_pat[((i & 3) << 2) | (j & 3)];

        int src_t = (t - s + 16) & 15; // (t - s) mod 16, s in [-7,8]
        int delta = src_t - t;         // shift in b-units

        v[u] = __builtin_nontemporal_load(&in[idx + delta * PLANE_F4]);
    }

#pragma unroll
    for (int u = 0; u < F4_PER_THREAD; ++u) {
        if (dst[u] < total_f4)
            __builtin_nontemporal_store(v[u], &out[dst[u]]);
    }
}

extern "C" void kernel_launch(void* const* d_in, const int* in_sizes, int n_in,
                              void* d_out, int out_size, void* d_ws, size_t ws_size,
                              hipStream_t stream) {
    const f4* in  = (const f4*)d_in[0];
    f4*       out = (f4*)d_out;

    int total_f4 = in_sizes[0] / 4;          // 9,633,792
    int per_block = BLOCK * F4_PER_THREAD;   // 1024 float4 per block
    int grid = (total_f4 + per_block - 1) / per_block;  // 9408 (exact)

    patch_shift_kernel<<<grid, BLOCK, 0, stream>>>(in, out, total_f4);
}

// Round 4
// 52.976 us; speedup vs baseline: 1.0636x; 1.0250x over previous
//
#include <hip/hip_runtime.h>

// Native 16B vector type accepted by __builtin_nontemporal_*.
typedef float f4 __attribute__((ext_vector_type(4)));

// Pattern 'D' temporal shifts per (row%4, col%4), mult = +1 (INV=False)
__device__ __constant__ int c_pat[16] = {
     0,  1,  2,  3,
    -1, -7,  4,  5,
     2, -4,  7,  6,
    -3, -5, -6,  8,
};

// Fixed problem geometry from setup_inputs():
//   batch_size=16, frame_len(T)=16, B=256, H=12, N=196 (14x14), c=64, fp32
constexpr int H   = 12;
constexpr int N   = 196;
constexpr int C   = 64;
constexpr int T   = 16;
constexpr int NS  = 14;
constexpr int PLANE_F4 = H * N * C / 4;    // float4 per b-slice = 37632
constexpr int F4_PER_THREAD = 8;
constexpr int BLOCK = 256;

// Grid is exact: 9,633,792 f4 / (256 threads * 8 f4) = 4704 blocks, no tail.
__global__ __launch_bounds__(BLOCK) void patch_shift_kernel(
    const f4* __restrict__ in, f4* __restrict__ out)
{
    int base = blockIdx.x * (BLOCK * F4_PER_THREAD) + threadIdx.x;

    f4 v[F4_PER_THREAD];

    // Issue all loads first (independent -> 8 outstanding per lane),
    // each sub-access wave-coalesced (stride BLOCK between sub-accesses).
#pragma unroll
    for (int u = 0; u < F4_PER_THREAD; ++u) {
        int idx = base + u * BLOCK;

        int row = idx >> 4;            // (b*H + h)*N + n
        int n   = row % N;             // patch index within 14x14 grid
        int bh  = row / N;
        int b   = bh / H;              // bs*T + t
        int t   = b & (T - 1);

        int i = n / NS;                // patch row
        int j = n - i * NS;            // patch col
        int s = c_pat[((i & 3) << 2) | (j & 3)];

        int src_t = (t - s + 16) & 15; // (t - s) mod 16, s in [-7,8]
        int delta = src_t - t;         // shift in b-units

        v[u] = __builtin_nontemporal_load(&in[idx + delta * PLANE_F4]);
    }

#pragma unroll
    for (int u = 0; u < F4_PER_THREAD; ++u) {
        __builtin_nontemporal_store(v[u], &out[base + u * BLOCK]);
    }
}

extern "C" void kernel_launch(void* const* d_in, const int* in_sizes, int n_in,
                              void* d_out, int out_size, void* d_ws, size_t ws_size,
                              hipStream_t stream) {
    const f4* in  = (const f4*)d_in[0];
    f4*       out = (f4*)d_out;

    int total_f4 = in_sizes[0] / 4;              // 9,633,792
    int per_block = BLOCK * F4_PER_THREAD;       // 2048 float4 per block
    int grid = total_f4 / per_block;             // 4704 (exact)

    patch_shift_kernel<<<grid, BLOCK, 0, stream>>>(in, out);
}